// Round 10
// baseline (142.579 us; speedup 1.0000x reference)
//
#include <hip/hip_runtime.h>
#include <math.h>

#define BB 128
#define LL 720
#define CC 321
#define HH 128
#define PP 336
#define MM 512
#define LPAD 768  // 720 padded to multiple of 64 (12 K-steps of 64)

typedef __attribute__((ext_vector_type(8))) short bf16x8;
typedef __attribute__((ext_vector_type(4))) float f32x4;

__device__ __forceinline__ short f2bf(float x) {
  unsigned u = __builtin_bit_cast(unsigned, x);
  u = (u + 0x7FFFu + ((u >> 16) & 1u)) >> 16;
  return (short)u;
}

// packed position of k-within-32-group: fragment lg*8 + half*4 + j
__device__ __forceinline__ int packpos(int kw) {
  return ((kw & 15) >> 2) * 8 + (kw >> 4) * 4 + (kw & 3);
}

// async global->LDS, 16 bytes per lane; lds ptr must be wave-uniform base
__device__ __forceinline__ void gload_lds16(const short* g, short* l) {
  __builtin_amdgcn_global_load_lds(
      (const __attribute__((address_space(1))) unsigned int*)g,
      (__attribute__((address_space(3))) unsigned int*)l, 16, 0, 0);
}

// ---------------------------------------------------------------------------
// Kernel 1 (v4): smeared weights -> combined W image for gemm1 v6.
//   wimg[s][h] is a 128-byte row of 16 16B slots; slot (g*8 + ((br*4+lg) ^
//   (h&7))) holds the packed 8-bf16 fragment (branch br, k-32-group g of
//   step s, lane-group lg): elems 0..3 = half0 (k = s*64+g*32+lg*4+jj),
//   4..7 = half1 (+16). XOR baked in -> bank-floor ds_read_b128 in gemm1.
// ---------------------------------------------------------------------------
__global__ void weff_kernel(const float* __restrict__ Ws1,
                            const float* __restrict__ Wt1,
                            short* __restrict__ wimg) {
  int idx = blockIdx.x * 256 + threadIdx.x;
  if (idx >= HH * LPAD) return;
  int j = idx % LPAD, h = idx / LPAD;
  int s = j >> 6, kw6 = j & 63, g = kw6 >> 5, kw = kw6 & 31;
  int half = kw >> 4, lg = (kw >> 2) & 3, jj = kw & 3;
  size_t base = ((size_t)(s * 128 + h)) * 128 + half * 4 + jj;
  int slotS = g * 8 + ((0 + lg) ^ (h & 7));
  int slotT = g * 8 + ((4 + lg) ^ (h & 7));
  if (j >= LL) {
    wimg[base + slotS * 8] = 0;
    wimg[base + slotT * 8] = 0;
    return;
  }
  float ss = 0.f, st = 0.f;
  if (j == 0) {
    for (int l = 0; l <= 12; ++l) {
      float w = 13.f - (float)l;
      ss += w * Ws1[h * LL + l];
      st += w * Wt1[h * LL + l];
    }
  } else if (j == LL - 1) {
    for (int d = 0; d <= 12; ++d) {
      float w = 13.f - (float)d;
      ss += w * Ws1[h * LL + LL - 1 - d];
      st += w * Wt1[h * LL + LL - 1 - d];
    }
  } else {
    int lo = j - 12 < 0 ? 0 : j - 12;
    int hi = j + 12 > LL - 1 ? LL - 1 : j + 12;
    for (int l = lo; l <= hi; ++l) {
      ss += Ws1[h * LL + l];
      st += Wt1[h * LL + l];
    }
  }
  ss *= (1.f / 25.f);
  st *= (1.f / 25.f);
  wimg[base + slotS * 8] = f2bf(Ws1[h * LL + j] - ss);
  wimg[base + slotT * 8] = f2bf(st);
}

// ---------------------------------------------------------------------------
// Kernel 1b: staged mem images for memenh (unchanged).
// ---------------------------------------------------------------------------
__global__ void memstage_kernel(const float* __restrict__ memS,
                                const float* __restrict__ memT,
                                short* __restrict__ stgS,
                                short* __restrict__ stgT) {
  int e = blockIdx.x * 256 + threadIdx.x;  // 0..32767
  int br = e >> 14;
  int s = e & 16383;
  const float* src = br ? memT : memS;
  short* dst = br ? stgT : stgS;
  int tt = s >> 11;                        // tile 0..7
  int c = s & 2047;
  int row = c >> 4, slot = c & 15;
  int sp = slot ^ (row & 7);
  int k = sp >> 2, lg = sp & 3;
  int ft = tt >> 1;
  short out[8];
  if ((tt & 1) == 0) {
    const float* r0 = src + (size_t)(ft * 128 + row) * 128 + k * 32 + lg * 4;
#pragma unroll
    for (int j = 0; j < 4; ++j) {
      out[j] = f2bf(r0[j]);
      out[j + 4] = f2bf(r0[16 + j]);
    }
  } else {
    int fbase = ft * 128 + k * 32 + lg * 4;
#pragma unroll
    for (int j = 0; j < 4; ++j) {
      out[j] = f2bf(src[(size_t)(fbase + j) * 128 + row]);
      out[j + 4] = f2bf(src[(size_t)(fbase + 16 + j) * 128 + row]);
    }
  }
  short4 a = make_short4(out[0], out[1], out[2], out[3]);
  short4 b = make_short4(out[4], out[5], out[6], out[7]);
  *(short4*)&dst[(size_t)s * 8] = a;
  *(short4*)&dst[(size_t)s * 8 + 4] = b;
}

// ---------------------------------------------------------------------------
// Kernel 1c: W2cat bf16 [336][512], fragment-packed per 32-group, + bias sum.
// ---------------------------------------------------------------------------
__global__ void w2cvt_kernel(const float* __restrict__ Ws2,
                             const float* __restrict__ Wt2,
                             const float* __restrict__ bs2,
                             const float* __restrict__ bt2,
                             short* __restrict__ W2b, float* __restrict__ b2) {
  int i = blockIdx.x * 256 + threadIdx.x;
  if (i < PP) b2[i] = bs2[i] + bt2[i];
  if (i >= PP * 512) return;
  int p = i >> 9, k = i & 511;
  float v = (k < 256) ? Ws2[p * 256 + k] : Wt2[p * 256 + (k - 256)];
  W2b[p * 512 + (k >> 5) * 32 + packpos(k & 31)] = f2bf(v);
}

// ---------------------------------------------------------------------------
// Kernel 2 (v6): MFMA dual-branch GEMM1 + sigmoid, BK=64 (12 steps).
//   256 thr / 4 waves; wave = 32 n x 64 h x 2 br; block = 64 n x 128 h.
//   W: per-step 32 KB tile copied with 8 global_load_lds/thread from the
//      pre-swizzled wimg (zero VALU staging); bank-floor b128 reads.
//   x: wave-coalesced reg gather (wave w loads k-octet w for 64 columns),
//      written to XOR-slotted 128B-row xlds; bank-floor reads/writes.
//   Both double-buffered, one barrier per 64-k step.
// ---------------------------------------------------------------------------
__global__ __launch_bounds__(256) void gemm1_mfma(
    const float* __restrict__ x, const short* __restrict__ wimg,
    const float* __restrict__ bs1, const float* __restrict__ bt1,
    short* __restrict__ r2s, short* __restrict__ r2t) {
  __shared__ __align__(16) short wlds[2][16384];  // 2 x 32 KB
  __shared__ __align__(16) short xlds[2][4096];   // 2 x 8 KB
  int tid = threadIdx.x;
  int w = tid >> 6, l = tid & 63, lr = l & 15, lg = l >> 4;
  int ngrp = w >> 1, hhalf = w & 1, hb = hhalf * 64;
  int nb = blockIdx.x * 64;  // 41088 = 642*64 exact
  int cc0 = ngrp * 32 + lr, cc1 = cc0 + 16;
  int n0 = nb + cc0, n1 = nb + cc1;

  // x gather: wave w = k-octet w, lane = column
  int xcc = l;                 // column 0..63 (tid&63 == l)
  int kg = w;                  // k-octet within 32-group
  int xn = nb + xcc;
  int xb_ = xn / CC, xc_ = xn - xb_ * CC;
  const float* xptr = x + (size_t)xb_ * (LL * CC) + xc_;
  // xlds write addresses (per g: two half-fragments)
  int xr = xcc >> 1, xodd = xcc & 1, xhalf = kg >> 1;
  int lgA = (kg & 1) * 2;
  int dxA = xr * 64 + (((xodd * 4 + lgA) ^ (xr & 7))) * 8 + xhalf * 4;
  int dxB = xr * 64 + (((xodd * 4 + lgA + 1) ^ (xr & 7))) * 8 + xhalf * 4;

  // W stage pointers: per-lane src, wave-uniform dst offset
  const short* wsrc0 = wimg + (size_t)(w * 512 + l * 8);

  f32x4 acc[2][4][2];  // [branch][ht][rt]
#pragma unroll
  for (int br = 0; br < 2; ++br)
#pragma unroll
    for (int i = 0; i < 4; ++i)
#pragma unroll
      for (int rt = 0; rt < 2; ++rt) acc[br][i][rt] = (f32x4){0.f, 0.f, 0.f, 0.f};

  // ---- prologue: stage step 0 ----
  {
#pragma unroll
    for (int i = 0; i < 8; ++i)
      gload_lds16(wsrc0 + i * 2048, &wlds[0][i * 2048 + w * 512]);
    float x0[16];
#pragma unroll
    for (int g = 0; g < 2; ++g)
#pragma unroll
      for (int m = 0; m < 8; ++m)
        x0[g * 8 + m] = xptr[(size_t)(g * 32 + kg * 8 + m) * CC];
#pragma unroll
    for (int g = 0; g < 2; ++g) {
      short4 a = make_short4(f2bf(x0[g * 8 + 0]), f2bf(x0[g * 8 + 1]),
                             f2bf(x0[g * 8 + 2]), f2bf(x0[g * 8 + 3]));
      short4 b = make_short4(f2bf(x0[g * 8 + 4]), f2bf(x0[g * 8 + 5]),
                             f2bf(x0[g * 8 + 6]), f2bf(x0[g * 8 + 7]));
      *(short4*)&xlds[0][g * 2048 + dxA] = a;
      *(short4*)&xlds[0][g * 2048 + dxB] = b;
    }
  }
  __syncthreads();

  int r0 = cc0 >> 1, r1 = cc1 >> 1;  // r1 = r0 + 8
  int sl0 = (((cc0 & 1) * 4 + lg) ^ (r0 & 7)) * 8;
  int sl1 = (((cc1 & 1) * 4 + lg) ^ (r1 & 7)) * 8;

  int cur = 0;
  for (int s = 0; s < 12; ++s) {
    // prefetch next step: x into regs (issued first), W via gload_lds
    float xn_[16];
    if (s < 11) {
      int k0 = (s + 1) * 64;
#pragma unroll
      for (int g = 0; g < 2; ++g)
#pragma unroll
        for (int m = 0; m < 8; ++m) {
          int k = k0 + g * 32 + kg * 8 + m;
          xn_[g * 8 + m] = (k < LL) ? xptr[(size_t)k * CC] : 0.f;
        }
      const short* ws = wsrc0 + (size_t)(s + 1) * 16384;
#pragma unroll
      for (int i = 0; i < 8; ++i)
        gload_lds16(ws + i * 2048, &wlds[cur ^ 1][i * 2048 + w * 512]);
    }

    // compute current step (2 k-groups of 32)
    const short* tw = &wlds[cur][0];
    const short* tx = &xlds[cur][0];
#pragma unroll
    for (int g = 0; g < 2; ++g) {
      bf16x8 bx0 = *(const bf16x8*)&tx[g * 2048 + r0 * 64 + sl0];
      bf16x8 bx1 = *(const bf16x8*)&tx[g * 2048 + r1 * 64 + sl1];
#pragma unroll
      for (int ht = 0; ht < 4; ++ht) {
        int h = hb + ht * 16 + lr;
        bf16x8 aS = *(const bf16x8*)&tw[h * 128 + (g * 8 + (lg ^ (h & 7))) * 8];
        bf16x8 aT =
            *(const bf16x8*)&tw[h * 128 + (g * 8 + ((4 + lg) ^ (h & 7))) * 8];
        acc[0][ht][0] =
            __builtin_amdgcn_mfma_f32_16x16x32_bf16(aS, bx0, acc[0][ht][0], 0, 0, 0);
        acc[0][ht][1] =
            __builtin_amdgcn_mfma_f32_16x16x32_bf16(aS, bx1, acc[0][ht][1], 0, 0, 0);
        acc[1][ht][0] =
            __builtin_amdgcn_mfma_f32_16x16x32_bf16(aT, bx0, acc[1][ht][0], 0, 0, 0);
        acc[1][ht][1] =
            __builtin_amdgcn_mfma_f32_16x16x32_bf16(aT, bx1, acc[1][ht][1], 0, 0, 0);
      }
    }

    // write next x tile (waits only on the x reg loads)
    if (s < 11) {
      short* txn = &xlds[cur ^ 1][0];
#pragma unroll
      for (int g = 0; g < 2; ++g) {
        short4 a = make_short4(f2bf(xn_[g * 8 + 0]), f2bf(xn_[g * 8 + 1]),
                               f2bf(xn_[g * 8 + 2]), f2bf(xn_[g * 8 + 3]));
        short4 b = make_short4(f2bf(xn_[g * 8 + 4]), f2bf(xn_[g * 8 + 5]),
                               f2bf(xn_[g * 8 + 6]), f2bf(xn_[g * 8 + 7]));
        *(short4*)&txn[g * 2048 + dxA] = a;
        *(short4*)&txn[g * 2048 + dxB] = b;
      }
    }
    __syncthreads();
    cur ^= 1;
  }

  // epilogue: sigmoid -> PACKED bf16 R at shorts [128..255] (same as r9)
#pragma unroll
  for (int rt = 0; rt < 2; ++rt) {
    int n = rt ? n1 : n0;
    short* rowS = r2s + (size_t)n * 256 + 128;
    short* rowT = r2t + (size_t)n * 256 + 128;
#pragma unroll
    for (int ht = 0; ht < 4; ++ht) {
      int h = hb + ht * 16 + lg * 4;
      int hbase = hb + ht * 16;
      int dst = (hbase >> 5) * 32 + lg * 8 + ((hbase >> 4) & 1) * 4;
      float4 bS = *(const float4*)&bs1[h];
      float4 bT = *(const float4*)&bt1[h];
      const float* pbS = &bS.x;
      const float* pbT = &bT.x;
      short4 ss, st;
      short* ps = &ss.x;
      short* pt = &st.x;
#pragma unroll
      for (int j = 0; j < 4; ++j) {
        ps[j] = f2bf(1.f / (1.f + __expf(-(acc[0][ht][rt][j] + pbS[j]))));
        pt[j] = f2bf(1.f / (1.f + __expf(-(acc[1][ht][rt][j] + pbT[j]))));
      }
      *(short4*)&rowS[dst] = ss;
      *(short4*)&rowT[dst] = st;
    }
  }
}

// ---------------------------------------------------------------------------
// Kernel 3: pipelined MFMA memory-enhance (unchanged from round 9).
// ---------------------------------------------------------------------------
__global__ __launch_bounds__(256) void memenh_mfma(
    const short* __restrict__ stgS, const short* __restrict__ stgT,
    short* __restrict__ r2s, short* __restrict__ r2t) {
  int br = blockIdx.y;
  const short* stg = br ? stgT : stgS;
  short* r2 = br ? r2t : r2s;

  __shared__ __align__(16) short buf[2][16384];  // 64 KB
  int tid = threadIdx.x;
  int l = tid & 63, lr = l & 15, lg = l >> 4;
  int wbase = tid & 192;
  int n = blockIdx.x * 64 + (tid >> 6) * 16 + lr;

  bf16x8 brag[4];
  {
    const short* rb = r2 + (size_t)n * 256 + 128;
#pragma unroll
    for (int k = 0; k < 4; ++k)
      brag[k] = *(const bf16x8*)&rb[k * 32 + lg * 8];
  }

#define STAGE(t, bsel)                                                        \
  {                                                                           \
    const short* g = stg + (size_t)(t)*16384;                                 \
    _Pragma("unroll") for (int i = 0; i < 8; ++i) {                           \
      gload_lds16(g + (size_t)(i * 256 + tid) * 8,                            \
                  &buf[bsel][(i * 256 + wbase) * 8]);                         \
    }                                                                         \
  }

  STAGE(0, 0);
  __syncthreads();

  f32x4 accO[8];
#pragma unroll
  for (int i = 0; i < 8; ++i) accO[i] = (f32x4){0.f, 0.f, 0.f, 0.f};
  bf16x8 pb[4];
  float ssum = 0.f;
  int cur = 0;

#pragma unroll
  for (int t = 0; t < 8; ++t) {
    if (t < 7) STAGE(t + 1, cur ^ 1);
    const short* tb = &buf[cur][0];
    if ((t & 1) == 0) {
      f32x4 sc[8];
#pragma unroll
      for (int ft16 = 0; ft16 < 8; ++ft16) {
        f32x4 a = {0.f, 0.f, 0.f, 0.f};
#pragma unroll
        for (int k = 0; k < 4; ++k) {
          int row = ft16 * 16 + lr;
          int slot = (4 * k + lg) ^ (row & 7);
          bf16x8 af = *(const bf16x8*)&tb[row * 128 + slot * 8];
          a = __builtin_amdgcn_mfma_f32_16x16x32_bf16(af, brag[k], a, 0, 0, 0);
        }
        sc[ft16] = a;
      }
#pragma unroll
      for (int i = 0; i < 8; ++i) {
        f32x4 v = sc[i];
#pragma unroll
        for (int j = 0; j < 4; ++j) {
          float e = __expf(v[j]);
          v[j] = e;
          ssum += e;
        }
        sc[i] = v;
      }
#pragma unroll
      for (int t4 = 0; t4 < 4; ++t4) {
        f32x4 e0 = sc[2 * t4], e1 = sc[2 * t4 + 1];
        bf16x8 f;
        f[0] = f2bf(e0[0]); f[1] = f2bf(e0[1]);
        f[2] = f2bf(e0[2]); f[3] = f2bf(e0[3]);
        f[4] = f2bf(e1[0]); f[5] = f2bf(e1[1]);
        f[6] = f2bf(e1[2]); f[7] = f2bf(e1[3]);
        pb[t4] = f;
      }
    } else {
#pragma unroll
      for (int dt = 0; dt < 8; ++dt) {
#pragma unroll
        for (int k = 0; k < 4; ++k) {
          int row = dt * 16 + lr;
          int slot = (4 * k + lg) ^ (row & 7);
          bf16x8 af = *(const bf16x8*)&tb[row * 128 + slot * 8];
          accO[dt] =
              __builtin_amdgcn_mfma_f32_16x16x32_bf16(af, pb[k], accO[dt], 0, 0, 0);
        }
      }
    }
    __syncthreads();
    cur ^= 1;
  }
#undef STAGE

  ssum += __shfl_xor(ssum, 16);
  ssum += __shfl_xor(ssum, 32);
  float inv = 1.f / ssum;
  short* rowO = r2 + (size_t)n * 256;
#pragma unroll
  for (int dt = 0; dt < 8; ++dt) {
    short4 o;
    o.x = f2bf(accO[dt][0] * inv);
    o.y = f2bf(accO[dt][1] * inv);
    o.z = f2bf(accO[dt][2] * inv);
    o.w = f2bf(accO[dt][3] * inv);
    *(short4*)&rowO[(dt >> 1) * 32 + lg * 8 + (dt & 1) * 4] = o;
  }
}

// ---------------------------------------------------------------------------
// Kernel 4: MFMA GEMM2 (bf16, K=512 concat, packed operands) + bias +
//   transposed store (unchanged from round 9).
// ---------------------------------------------------------------------------
__global__ __launch_bounds__(512) void gemm2_mfma(
    const short* __restrict__ r2s, const short* __restrict__ r2t,
    const short* __restrict__ W2b,  // [336][512] bf16 packed
    const float* __restrict__ b2,   // [336]
    float* __restrict__ out) {
  __shared__ __align__(16) short w2lds[2][112 * 40];  // 17.9 KB
  int tid = threadIdx.x;
  int w = tid >> 6, l = tid & 63, lr = l & 15, lg = l >> 4;
  int p0 = blockIdx.y * 112;
  int n = blockIdx.x * 128 + w * 16 + lr;
  int b = n / CC, c = n - b * CC;
  const short* rs = r2s + (size_t)n * 256;
  const short* rt = r2t + (size_t)n * 256;

  bool dostage = tid < 448;
  int row = tid >> 2, q = tid & 3;
  const short* gW = W2b + (size_t)(p0 + row) * 512 + q * 8;
  int doff = row * 40 + q * 8;

  f32x4 acc[7];
#pragma unroll
  for (int i = 0; i < 7; ++i) acc[i] = (f32x4){0.f, 0.f, 0.f, 0.f};

  if (dostage) *(int4*)&w2lds[0][doff] = *(const int4*)gW;
  __syncthreads();

  int cur = 0;
  for (int step = 0; step < 16; ++step) {
    int k0 = step * 32;
    const short* rrow = ((k0 < 256) ? rs : rt) + (k0 & 255);
    bf16x8 bfr = *(const bf16x8*)&rrow[lg * 8];
    int4 nxt = {0, 0, 0, 0};
    if (step < 15 && dostage) nxt = *(const int4*)(gW + (step + 1) * 32);
    const short* tw = &w2lds[cur][0];
#pragma unroll
    for (int pt = 0; pt < 7; ++pt) {
      bf16x8 a = *(const bf16x8*)&tw[(pt * 16 + lr) * 40 + lg * 8];
      acc[pt] = __builtin_amdgcn_mfma_f32_16x16x32_bf16(a, bfr, acc[pt], 0, 0, 0);
    }
    if (step < 15 && dostage) *(int4*)&w2lds[cur ^ 1][doff] = nxt;
    __syncthreads();
    cur ^= 1;
  }

  size_t obase = (size_t)b * ((size_t)PP * CC) + c;
#pragma unroll
  for (int pt = 0; pt < 7; ++pt) {
    int p = p0 + pt * 16 + lg * 4;
    float4 bias = *(const float4*)&b2[p];
    const float* pb = &bias.x;
#pragma unroll
    for (int j = 0; j < 4; ++j) {
      out[obase + (size_t)(p + j) * CC] = acc[pt][j] + pb[j];
    }
  }
}

// ---------------------------------------------------------------------------
extern "C" void kernel_launch(void* const* d_in, const int* in_sizes, int n_in,
                              void* d_out, int out_size, void* d_ws, size_t ws_size,
                              hipStream_t stream) {
  const float* x    = (const float*)d_in[0];
  const float* Ws1  = (const float*)d_in[1];
  const float* bs1  = (const float*)d_in[2];
  const float* Ws2  = (const float*)d_in[3];
  const float* bs2  = (const float*)d_in[4];
  const float* Wt1  = (const float*)d_in[5];
  const float* bt1  = (const float*)d_in[6];
  const float* Wt2  = (const float*)d_in[7];
  const float* bt2  = (const float*)d_in[8];
  const float* memS = (const float*)d_in[9];
  const float* memT = (const float*)d_in[10];
  float* out = (float*)d_out;

  const size_t N = (size_t)BB * CC;          // 41088
  short* r2s  = (short*)d_ws;                // [N][256] bf16 packed: [O | R]
  short* r2t  = r2s + N * 256;
  short* wimg = r2t + N * 256;               // [12][128][64sh*2] = 384 KB
  short* stgS = wimg + (size_t)12 * 128 * 128;
  short* stgT = stgS + (size_t)16384 * 8;
  short* W2b  = stgT + (size_t)16384 * 8;    // [336][512] bf16 packed
  float* b2   = (float*)(W2b + (size_t)PP * 512);

  // 1. precompute weights / staged conversions
  weff_kernel<<<(HH * LPAD) / 256, 256, 0, stream>>>(Ws1, Wt1, wimg);
  memstage_kernel<<<128, 256, 0, stream>>>(memS, memT, stgS, stgT);
  w2cvt_kernel<<<(PP * 512) / 256, 256, 0, stream>>>(Ws2, Wt2, bs2, bt2, W2b, b2);

  // 2. MFMA GEMM1 + sigmoid (both branches), BK=64, grid 642
  gemm1_mfma<<<642, 256, 0, stream>>>(x, wimg, bs1, bt1, r2s, r2t);

  // 3. pipelined MFMA memory enhance, both branches in one dispatch
  dim3 g3(642, 2);
  memenh_mfma<<<g3, 256, 0, stream>>>(stgS, stgT, r2s, r2t);

  // 4. MFMA GEMM2 + bias + transposed store
  dim3 g2(321, 3);
  gemm2_mfma<<<g2, 512, 0, stream>>>(r2s, r2t, W2b, b2, out);
}

// Round 11
// 141.695 us; speedup vs baseline: 1.0062x; 1.0062x over previous
//
#include <hip/hip_runtime.h>
#include <math.h>

#define BB 128
#define LL 720
#define CC 321
#define HH 128
#define PP 336
#define MM 512
#define LPAD 768  // 720 padded to multiple of 64 (12 K-steps of 64)

typedef __attribute__((ext_vector_type(8))) short bf16x8;
typedef __attribute__((ext_vector_type(4))) float f32x4;

__device__ __forceinline__ short f2bf(float x) {
  unsigned u = __builtin_bit_cast(unsigned, x);
  u = (u + 0x7FFFu + ((u >> 16) & 1u)) >> 16;
  return (short)u;
}

// packed position of k-within-32-group: fragment lg*8 + half*4 + j
__device__ __forceinline__ int packpos(int kw) {
  return ((kw & 15) >> 2) * 8 + (kw >> 4) * 4 + (kw & 3);
}

// async global->LDS, 16 bytes per lane; lds ptr must be wave-uniform base
__device__ __forceinline__ void gload_lds16(const short* g, short* l) {
  __builtin_amdgcn_global_load_lds(
      (const __attribute__((address_space(1))) unsigned int*)g,
      (__attribute__((address_space(3))) unsigned int*)l, 16, 0, 0);
}

// ---------------------------------------------------------------------------
// Kernel 1 (v4): smeared weights -> combined W image for gemm1 (unchanged).
// ---------------------------------------------------------------------------
__global__ void weff_kernel(const float* __restrict__ Ws1,
                            const float* __restrict__ Wt1,
                            short* __restrict__ wimg) {
  int idx = blockIdx.x * 256 + threadIdx.x;
  if (idx >= HH * LPAD) return;
  int j = idx % LPAD, h = idx / LPAD;
  int s = j >> 6, kw6 = j & 63, g = kw6 >> 5, kw = kw6 & 31;
  int half = kw >> 4, lg = (kw >> 2) & 3, jj = kw & 3;
  size_t base = ((size_t)(s * 128 + h)) * 128 + half * 4 + jj;
  int slotS = g * 8 + ((0 + lg) ^ (h & 7));
  int slotT = g * 8 + ((4 + lg) ^ (h & 7));
  if (j >= LL) {
    wimg[base + slotS * 8] = 0;
    wimg[base + slotT * 8] = 0;
    return;
  }
  float ss = 0.f, st = 0.f;
  if (j == 0) {
    for (int l = 0; l <= 12; ++l) {
      float w = 13.f - (float)l;
      ss += w * Ws1[h * LL + l];
      st += w * Wt1[h * LL + l];
    }
  } else if (j == LL - 1) {
    for (int d = 0; d <= 12; ++d) {
      float w = 13.f - (float)d;
      ss += w * Ws1[h * LL + LL - 1 - d];
      st += w * Wt1[h * LL + LL - 1 - d];
    }
  } else {
    int lo = j - 12 < 0 ? 0 : j - 12;
    int hi = j + 12 > LL - 1 ? LL - 1 : j + 12;
    for (int l = lo; l <= hi; ++l) {
      ss += Ws1[h * LL + l];
      st += Wt1[h * LL + l];
    }
  }
  ss *= (1.f / 25.f);
  st *= (1.f / 25.f);
  wimg[base + slotS * 8] = f2bf(Ws1[h * LL + j] - ss);
  wimg[base + slotT * 8] = f2bf(st);
}

// ---------------------------------------------------------------------------
// Kernel 1b: staged mem images for memenh (unchanged).
// ---------------------------------------------------------------------------
__global__ void memstage_kernel(const float* __restrict__ memS,
                                const float* __restrict__ memT,
                                short* __restrict__ stgS,
                                short* __restrict__ stgT) {
  int e = blockIdx.x * 256 + threadIdx.x;  // 0..32767
  int br = e >> 14;
  int s = e & 16383;
  const float* src = br ? memT : memS;
  short* dst = br ? stgT : stgS;
  int tt = s >> 11;                        // tile 0..7
  int c = s & 2047;
  int row = c >> 4, slot = c & 15;
  int sp = slot ^ (row & 7);
  int k = sp >> 2, lg = sp & 3;
  int ft = tt >> 1;
  short out[8];
  if ((tt & 1) == 0) {
    const float* r0 = src + (size_t)(ft * 128 + row) * 128 + k * 32 + lg * 4;
#pragma unroll
    for (int j = 0; j < 4; ++j) {
      out[j] = f2bf(r0[j]);
      out[j + 4] = f2bf(r0[16 + j]);
    }
  } else {
    int fbase = ft * 128 + k * 32 + lg * 4;
#pragma unroll
    for (int j = 0; j < 4; ++j) {
      out[j] = f2bf(src[(size_t)(fbase + j) * 128 + row]);
      out[j + 4] = f2bf(src[(size_t)(fbase + 16 + j) * 128 + row]);
    }
  }
  short4 a = make_short4(out[0], out[1], out[2], out[3]);
  short4 b = make_short4(out[4], out[5], out[6], out[7]);
  *(short4*)&dst[(size_t)s * 8] = a;
  *(short4*)&dst[(size_t)s * 8 + 4] = b;
}

// ---------------------------------------------------------------------------
// Kernel 1c: W2cat bf16 [336][512], fragment-packed per 32-group, + bias sum.
// ---------------------------------------------------------------------------
__global__ void w2cvt_kernel(const float* __restrict__ Ws2,
                             const float* __restrict__ Wt2,
                             const float* __restrict__ bs2,
                             const float* __restrict__ bt2,
                             short* __restrict__ W2b, float* __restrict__ b2) {
  int i = blockIdx.x * 256 + threadIdx.x;
  if (i < PP) b2[i] = bs2[i] + bt2[i];
  if (i >= PP * 512) return;
  int p = i >> 9, k = i & 511;
  float v = (k < 256) ? Ws2[p * 256 + k] : Wt2[p * 256 + (k - 256)];
  W2b[p * 512 + (k >> 5) * 32 + packpos(k & 31)] = f2bf(v);
}

// ---------------------------------------------------------------------------
// Kernel 2 (v7): identical structure to v6 (BK=64, gload_lds W, XOR x-LDS)
//   but with __launch_bounds__(256, 2): LDS (80 KB) already caps occupancy
//   at 2 blocks/CU = 2 waves/EU, so raising the VGPR budget to 256 is free
//   and lets the allocator keep all 16 x-prefetch loads + W stage in flight
//   instead of serializing them in register-starved batches (r7-r10 all
//   showed VGPR 76-96 with identical ~82-87 us — the register throttle).
// ---------------------------------------------------------------------------
__global__ __launch_bounds__(256, 2) void gemm1_mfma(
    const float* __restrict__ x, const short* __restrict__ wimg,
    const float* __restrict__ bs1, const float* __restrict__ bt1,
    short* __restrict__ r2s, short* __restrict__ r2t) {
  __shared__ __align__(16) short wlds[2][16384];  // 2 x 32 KB
  __shared__ __align__(16) short xlds[2][4096];   // 2 x 8 KB
  int tid = threadIdx.x;
  int w = tid >> 6, l = tid & 63, lr = l & 15, lg = l >> 4;
  int ngrp = w >> 1, hhalf = w & 1, hb = hhalf * 64;
  int nb = blockIdx.x * 64;  // 41088 = 642*64 exact
  int cc0 = ngrp * 32 + lr, cc1 = cc0 + 16;
  int n0 = nb + cc0, n1 = nb + cc1;

  // x gather: wave w = k-octet w, lane = column
  int xcc = l;
  int kg = w;
  int xn = nb + xcc;
  int xb_ = xn / CC, xc_ = xn - xb_ * CC;
  const float* xptr = x + (size_t)xb_ * (LL * CC) + xc_;
  int xr = xcc >> 1, xodd = xcc & 1, xhalf = kg >> 1;
  int lgA = (kg & 1) * 2;
  int dxA = xr * 64 + (((xodd * 4 + lgA) ^ (xr & 7))) * 8 + xhalf * 4;
  int dxB = xr * 64 + (((xodd * 4 + lgA + 1) ^ (xr & 7))) * 8 + xhalf * 4;

  const short* wsrc0 = wimg + (size_t)(w * 512 + l * 8);

  f32x4 acc[2][4][2];  // [branch][ht][rt]
#pragma unroll
  for (int br = 0; br < 2; ++br)
#pragma unroll
    for (int i = 0; i < 4; ++i)
#pragma unroll
      for (int rt = 0; rt < 2; ++rt) acc[br][i][rt] = (f32x4){0.f, 0.f, 0.f, 0.f};

  // ---- prologue: stage step 0 ----
  {
#pragma unroll
    for (int i = 0; i < 8; ++i)
      gload_lds16(wsrc0 + i * 2048, &wlds[0][i * 2048 + w * 512]);
    float x0[16];
#pragma unroll
    for (int g = 0; g < 2; ++g)
#pragma unroll
      for (int m = 0; m < 8; ++m)
        x0[g * 8 + m] = xptr[(size_t)(g * 32 + kg * 8 + m) * CC];
#pragma unroll
    for (int g = 0; g < 2; ++g) {
      short4 a = make_short4(f2bf(x0[g * 8 + 0]), f2bf(x0[g * 8 + 1]),
                             f2bf(x0[g * 8 + 2]), f2bf(x0[g * 8 + 3]));
      short4 b = make_short4(f2bf(x0[g * 8 + 4]), f2bf(x0[g * 8 + 5]),
                             f2bf(x0[g * 8 + 6]), f2bf(x0[g * 8 + 7]));
      *(short4*)&xlds[0][g * 2048 + dxA] = a;
      *(short4*)&xlds[0][g * 2048 + dxB] = b;
    }
  }
  __syncthreads();

  int r0 = cc0 >> 1, r1 = cc1 >> 1;
  int sl0 = (((cc0 & 1) * 4 + lg) ^ (r0 & 7)) * 8;
  int sl1 = (((cc1 & 1) * 4 + lg) ^ (r1 & 7)) * 8;

  int cur = 0;
  for (int s = 0; s < 12; ++s) {
    // prefetch next step: x into regs (issued first), W via gload_lds
    float xn_[16];
    if (s < 11) {
      int k0 = (s + 1) * 64;
#pragma unroll
      for (int g = 0; g < 2; ++g)
#pragma unroll
        for (int m = 0; m < 8; ++m) {
          int k = k0 + g * 32 + kg * 8 + m;
          xn_[g * 8 + m] = (k < LL) ? xptr[(size_t)k * CC] : 0.f;
        }
      const short* ws = wsrc0 + (size_t)(s + 1) * 16384;
#pragma unroll
      for (int i = 0; i < 8; ++i)
        gload_lds16(ws + i * 2048, &wlds[cur ^ 1][i * 2048 + w * 512]);
    }

    // compute current step (2 k-groups of 32)
    const short* tw = &wlds[cur][0];
    const short* tx = &xlds[cur][0];
#pragma unroll
    for (int g = 0; g < 2; ++g) {
      bf16x8 bx0 = *(const bf16x8*)&tx[g * 2048 + r0 * 64 + sl0];
      bf16x8 bx1 = *(const bf16x8*)&tx[g * 2048 + r1 * 64 + sl1];
#pragma unroll
      for (int ht = 0; ht < 4; ++ht) {
        int h = hb + ht * 16 + lr;
        bf16x8 aS = *(const bf16x8*)&tw[h * 128 + (g * 8 + (lg ^ (h & 7))) * 8];
        bf16x8 aT =
            *(const bf16x8*)&tw[h * 128 + (g * 8 + ((4 + lg) ^ (h & 7))) * 8];
        acc[0][ht][0] =
            __builtin_amdgcn_mfma_f32_16x16x32_bf16(aS, bx0, acc[0][ht][0], 0, 0, 0);
        acc[0][ht][1] =
            __builtin_amdgcn_mfma_f32_16x16x32_bf16(aS, bx1, acc[0][ht][1], 0, 0, 0);
        acc[1][ht][0] =
            __builtin_amdgcn_mfma_f32_16x16x32_bf16(aT, bx0, acc[1][ht][0], 0, 0, 0);
        acc[1][ht][1] =
            __builtin_amdgcn_mfma_f32_16x16x32_bf16(aT, bx1, acc[1][ht][1], 0, 0, 0);
      }
    }

    // write next x tile (waits only on the x reg loads)
    if (s < 11) {
      short* txn = &xlds[cur ^ 1][0];
#pragma unroll
      for (int g = 0; g < 2; ++g) {
        short4 a = make_short4(f2bf(xn_[g * 8 + 0]), f2bf(xn_[g * 8 + 1]),
                               f2bf(xn_[g * 8 + 2]), f2bf(xn_[g * 8 + 3]));
        short4 b = make_short4(f2bf(xn_[g * 8 + 4]), f2bf(xn_[g * 8 + 5]),
                               f2bf(xn_[g * 8 + 6]), f2bf(xn_[g * 8 + 7]));
        *(short4*)&txn[g * 2048 + dxA] = a;
        *(short4*)&txn[g * 2048 + dxB] = b;
      }
    }
    __syncthreads();
    cur ^= 1;
  }

  // epilogue: sigmoid -> PACKED bf16 R at shorts [128..255]
#pragma unroll
  for (int rt = 0; rt < 2; ++rt) {
    int n = rt ? n1 : n0;
    short* rowS = r2s + (size_t)n * 256 + 128;
    short* rowT = r2t + (size_t)n * 256 + 128;
#pragma unroll
    for (int ht = 0; ht < 4; ++ht) {
      int h = hb + ht * 16 + lg * 4;
      int hbase = hb + ht * 16;
      int dst = (hbase >> 5) * 32 + lg * 8 + ((hbase >> 4) & 1) * 4;
      float4 bS = *(const float4*)&bs1[h];
      float4 bT = *(const float4*)&bt1[h];
      const float* pbS = &bS.x;
      const float* pbT = &bT.x;
      short4 ss, st;
      short* ps = &ss.x;
      short* pt = &st.x;
#pragma unroll
      for (int j = 0; j < 4; ++j) {
        ps[j] = f2bf(1.f / (1.f + __expf(-(acc[0][ht][rt][j] + pbS[j]))));
        pt[j] = f2bf(1.f / (1.f + __expf(-(acc[1][ht][rt][j] + pbT[j]))));
      }
      *(short4*)&rowS[dst] = ss;
      *(short4*)&rowT[dst] = st;
    }
  }
}

// ---------------------------------------------------------------------------
// Kernel 3: pipelined MFMA memory-enhance (unchanged).
// ---------------------------------------------------------------------------
__global__ __launch_bounds__(256) void memenh_mfma(
    const short* __restrict__ stgS, const short* __restrict__ stgT,
    short* __restrict__ r2s, short* __restrict__ r2t) {
  int br = blockIdx.y;
  const short* stg = br ? stgT : stgS;
  short* r2 = br ? r2t : r2s;

  __shared__ __align__(16) short buf[2][16384];  // 64 KB
  int tid = threadIdx.x;
  int l = tid & 63, lr = l & 15, lg = l >> 4;
  int wbase = tid & 192;
  int n = blockIdx.x * 64 + (tid >> 6) * 16 + lr;

  bf16x8 brag[4];
  {
    const short* rb = r2 + (size_t)n * 256 + 128;
#pragma unroll
    for (int k = 0; k < 4; ++k)
      brag[k] = *(const bf16x8*)&rb[k * 32 + lg * 8];
  }

#define STAGE(t, bsel)                                                        \
  {                                                                           \
    const short* g = stg + (size_t)(t)*16384;                                 \
    _Pragma("unroll") for (int i = 0; i < 8; ++i) {                           \
      gload_lds16(g + (size_t)(i * 256 + tid) * 8,                            \
                  &buf[bsel][(i * 256 + wbase) * 8]);                         \
    }                                                                         \
  }

  STAGE(0, 0);
  __syncthreads();

  f32x4 accO[8];
#pragma unroll
  for (int i = 0; i < 8; ++i) accO[i] = (f32x4){0.f, 0.f, 0.f, 0.f};
  bf16x8 pb[4];
  float ssum = 0.f;
  int cur = 0;

#pragma unroll
  for (int t = 0; t < 8; ++t) {
    if (t < 7) STAGE(t + 1, cur ^ 1);
    const short* tb = &buf[cur][0];
    if ((t & 1) == 0) {
      f32x4 sc[8];
#pragma unroll
      for (int ft16 = 0; ft16 < 8; ++ft16) {
        f32x4 a = {0.f, 0.f, 0.f, 0.f};
#pragma unroll
        for (int k = 0; k < 4; ++k) {
          int row = ft16 * 16 + lr;
          int slot = (4 * k + lg) ^ (row & 7);
          bf16x8 af = *(const bf16x8*)&tb[row * 128 + slot * 8];
          a = __builtin_amdgcn_mfma_f32_16x16x32_bf16(af, brag[k], a, 0, 0, 0);
        }
        sc[ft16] = a;
      }
#pragma unroll
      for (int i = 0; i < 8; ++i) {
        f32x4 v = sc[i];
#pragma unroll
        for (int j = 0; j < 4; ++j) {
          float e = __expf(v[j]);
          v[j] = e;
          ssum += e;
        }
        sc[i] = v;
      }
#pragma unroll
      for (int t4 = 0; t4 < 4; ++t4) {
        f32x4 e0 = sc[2 * t4], e1 = sc[2 * t4 + 1];
        bf16x8 f;
        f[0] = f2bf(e0[0]); f[1] = f2bf(e0[1]);
        f[2] = f2bf(e0[2]); f[3] = f2bf(e0[3]);
        f[4] = f2bf(e1[0]); f[5] = f2bf(e1[1]);
        f[6] = f2bf(e1[2]); f[7] = f2bf(e1[3]);
        pb[t4] = f;
      }
    } else {
#pragma unroll
      for (int dt = 0; dt < 8; ++dt) {
#pragma unroll
        for (int k = 0; k < 4; ++k) {
          int row = dt * 16 + lr;
          int slot = (4 * k + lg) ^ (row & 7);
          bf16x8 af = *(const bf16x8*)&tb[row * 128 + slot * 8];
          accO[dt] =
              __builtin_amdgcn_mfma_f32_16x16x32_bf16(af, pb[k], accO[dt], 0, 0, 0);
        }
      }
    }
    __syncthreads();
    cur ^= 1;
  }
#undef STAGE

  ssum += __shfl_xor(ssum, 16);
  ssum += __shfl_xor(ssum, 32);
  float inv = 1.f / ssum;
  short* rowO = r2 + (size_t)n * 256;
#pragma unroll
  for (int dt = 0; dt < 8; ++dt) {
    short4 o;
    o.x = f2bf(accO[dt][0] * inv);
    o.y = f2bf(accO[dt][1] * inv);
    o.z = f2bf(accO[dt][2] * inv);
    o.w = f2bf(accO[dt][3] * inv);
    *(short4*)&rowO[(dt >> 1) * 32 + lg * 8 + (dt & 1) * 4] = o;
  }
}

// ---------------------------------------------------------------------------
// Kernel 4: MFMA GEMM2 (bf16, K=512 concat, packed operands) + bias +
//   transposed store (unchanged).
// ---------------------------------------------------------------------------
__global__ __launch_bounds__(512) void gemm2_mfma(
    const short* __restrict__ r2s, const short* __restrict__ r2t,
    const short* __restrict__ W2b,  // [336][512] bf16 packed
    const float* __restrict__ b2,   // [336]
    float* __restrict__ out) {
  __shared__ __align__(16) short w2lds[2][112 * 40];  // 17.9 KB
  int tid = threadIdx.x;
  int w = tid >> 6, l = tid & 63, lr = l & 15, lg = l >> 4;
  int p0 = blockIdx.y * 112;
  int n = blockIdx.x * 128 + w * 16 + lr;
  int b = n / CC, c = n - b * CC;
  const short* rs = r2s + (size_t)n * 256;
  const short* rt = r2t + (size_t)n * 256;

  bool dostage = tid < 448;
  int row = tid >> 2, q = tid & 3;
  const short* gW = W2b + (size_t)(p0 + row) * 512 + q * 8;
  int doff = row * 40 + q * 8;

  f32x4 acc[7];
#pragma unroll
  for (int i = 0; i < 7; ++i) acc[i] = (f32x4){0.f, 0.f, 0.f, 0.f};

  if (dostage) *(int4*)&w2lds[0][doff] = *(const int4*)gW;
  __syncthreads();

  int cur = 0;
  for (int step = 0; step < 16; ++step) {
    int k0 = step * 32;
    const short* rrow = ((k0 < 256) ? rs : rt) + (k0 & 255);
    bf16x8 bfr = *(const bf16x8*)&rrow[lg * 8];
    int4 nxt = {0, 0, 0, 0};
    if (step < 15 && dostage) nxt = *(const int4*)(gW + (step + 1) * 32);
    const short* tw = &w2lds[cur][0];
#pragma unroll
    for (int pt = 0; pt < 7; ++pt) {
      bf16x8 a = *(const bf16x8*)&tw[(pt * 16 + lr) * 40 + lg * 8];
      acc[pt] = __builtin_amdgcn_mfma_f32_16x16x32_bf16(a, bfr, acc[pt], 0, 0, 0);
    }
    if (step < 15 && dostage) *(int4*)&w2lds[cur ^ 1][doff] = nxt;
    __syncthreads();
    cur ^= 1;
  }

  size_t obase = (size_t)b * ((size_t)PP * CC) + c;
#pragma unroll
  for (int pt = 0; pt < 7; ++pt) {
    int p = p0 + pt * 16 + lg * 4;
    float4 bias = *(const float4*)&b2[p];
    const float* pb = &bias.x;
#pragma unroll
    for (int j = 0; j < 4; ++j) {
      out[obase + (size_t)(p + j) * CC] = acc[pt][j] + pb[j];
    }
  }
}

// ---------------------------------------------------------------------------
extern "C" void kernel_launch(void* const* d_in, const int* in_sizes, int n_in,
                              void* d_out, int out_size, void* d_ws, size_t ws_size,
                              hipStream_t stream) {
  const float* x    = (const float*)d_in[0];
  const float* Ws1  = (const float*)d_in[1];
  const float* bs1  = (const float*)d_in[2];
  const float* Ws2  = (const float*)d_in[3];
  const float* bs2  = (const float*)d_in[4];
  const float* Wt1  = (const float*)d_in[5];
  const float* bt1  = (const float*)d_in[6];
  const float* Wt2  = (const float*)d_in[7];
  const float* bt2  = (const float*)d_in[8];
  const float* memS = (const float*)d_in[9];
  const float* memT = (const float*)d_in[10];
  float* out = (float*)d_out;

  const size_t N = (size_t)BB * CC;          // 41088
  short* r2s  = (short*)d_ws;                // [N][256] bf16 packed: [O | R]
  short* r2t  = r2s + N * 256;
  short* wimg = r2t + N * 256;               // [12][128][128B] = 384 KB
  short* stgS = wimg + (size_t)12 * 128 * 128;
  short* stgT = stgS + (size_t)16384 * 8;
  short* W2b  = stgT + (size_t)16384 * 8;    // [336][512] bf16 packed
  float* b2   = (float*)(W2b + (size_t)PP * 512);

  // 1. precompute weights / staged conversions
  weff_kernel<<<(HH * LPAD) / 256, 256, 0, stream>>>(Ws1, Wt1, wimg);
  memstage_kernel<<<128, 256, 0, stream>>>(memS, memT, stgS, stgT);
  w2cvt_kernel<<<(PP * 512) / 256, 256, 0, stream>>>(Ws2, Wt2, bs2, bt2, W2b, b2);

  // 2. MFMA GEMM1 + sigmoid (both branches), BK=64, grid 642
  gemm1_mfma<<<642, 256, 0, stream>>>(x, wimg, bs1, bt1, r2s, r2t);

  // 3. pipelined MFMA memory enhance, both branches in one dispatch
  dim3 g3(642, 2);
  memenh_mfma<<<g3, 256, 0, stream>>>(stgS, stgT, r2s, r2t);

  // 4. MFMA GEMM2 + bias + transposed store
  dim3 g2(321, 3);
  gemm2_mfma<<<g2, 512, 0, stream>>>(r2s, r2t, W2b, b2, out);
}

// Round 12
// 141.597 us; speedup vs baseline: 1.0069x; 1.0007x over previous
//
#include <hip/hip_runtime.h>
#include <math.h>

#define BB 128
#define LL 720
#define CC 321
#define HH 128
#define PP 336
#define MM 512
#define NSTEP 23   // K-steps of 32 (736 = 23*32, zero-padded past 720)

typedef __attribute__((ext_vector_type(8))) short bf16x8;
typedef __attribute__((ext_vector_type(4))) float f32x4;

__device__ __forceinline__ short f2bf(float x) {
  unsigned u = __builtin_bit_cast(unsigned, x);
  u = (u + 0x7FFFu + ((u >> 16) & 1u)) >> 16;
  return (short)u;
}

// packed position of k-within-32-group: fragment lg*8 + half*4 + j
__device__ __forceinline__ int packpos(int kw) {
  return ((kw & 15) >> 2) * 8 + (kw >> 4) * 4 + (kw & 3);
}

// async global->LDS, 16 bytes per lane; lds ptr must be wave-uniform base
__device__ __forceinline__ void gload_lds16(const short* g, short* l) {
  __builtin_amdgcn_global_load_lds(
      (const __attribute__((address_space(1))) unsigned int*)g,
      (__attribute__((address_space(3))) unsigned int*)l, 16, 0, 0);
}

// ---------------------------------------------------------------------------
// Kernel 1 (v5): smeared weights -> W image for gemm1 v8 (BK=32).
//   wimg[s][h] = 64-short (128B) row of 8 16B slots; slot (br*4+lg)^(h&7)
//   holds shorts: half*4+jj = bf16(Weff_br[h][s*32 + half*16 + lg*4 + jj]).
//   Total 23 steps x 16KB = 368 KB.
// ---------------------------------------------------------------------------
__global__ void weff_kernel(const float* __restrict__ Ws1,
                            const float* __restrict__ Wt1,
                            short* __restrict__ wimg) {
  int idx = blockIdx.x * 256 + threadIdx.x;
  if (idx >= HH * NSTEP * 32) return;
  int j = idx % (NSTEP * 32), h = idx / (NSTEP * 32);
  int s = j >> 5, kw = j & 31;
  int half = kw >> 4, lg = (kw >> 2) & 3, jj = kw & 3;
  size_t base = ((size_t)(s * 128 + h)) * 64 + half * 4 + jj;
  int slotS = (0 + lg) ^ (h & 7);
  int slotT = (4 + lg) ^ (h & 7);
  if (j >= LL) {
    wimg[base + slotS * 8] = 0;
    wimg[base + slotT * 8] = 0;
    return;
  }
  float ss = 0.f, st = 0.f;
  if (j == 0) {
    for (int l = 0; l <= 12; ++l) {
      float w = 13.f - (float)l;
      ss += w * Ws1[h * LL + l];
      st += w * Wt1[h * LL + l];
    }
  } else if (j == LL - 1) {
    for (int d = 0; d <= 12; ++d) {
      float w = 13.f - (float)d;
      ss += w * Ws1[h * LL + LL - 1 - d];
      st += w * Wt1[h * LL + LL - 1 - d];
    }
  } else {
    int lo = j - 12 < 0 ? 0 : j - 12;
    int hi = j + 12 > LL - 1 ? LL - 1 : j + 12;
    for (int l = lo; l <= hi; ++l) {
      ss += Ws1[h * LL + l];
      st += Wt1[h * LL + l];
    }
  }
  ss *= (1.f / 25.f);
  st *= (1.f / 25.f);
  wimg[base + slotS * 8] = f2bf(Ws1[h * LL + j] - ss);
  wimg[base + slotT * 8] = f2bf(st);
}

// ---------------------------------------------------------------------------
// Kernel 1b: staged mem images for memenh (unchanged).
// ---------------------------------------------------------------------------
__global__ void memstage_kernel(const float* __restrict__ memS,
                                const float* __restrict__ memT,
                                short* __restrict__ stgS,
                                short* __restrict__ stgT) {
  int e = blockIdx.x * 256 + threadIdx.x;  // 0..32767
  int br = e >> 14;
  int s = e & 16383;
  const float* src = br ? memT : memS;
  short* dst = br ? stgT : stgS;
  int tt = s >> 11;                        // tile 0..7
  int c = s & 2047;
  int row = c >> 4, slot = c & 15;
  int sp = slot ^ (row & 7);
  int k = sp >> 2, lg = sp & 3;
  int ft = tt >> 1;
  short out[8];
  if ((tt & 1) == 0) {
    const float* r0 = src + (size_t)(ft * 128 + row) * 128 + k * 32 + lg * 4;
#pragma unroll
    for (int j = 0; j < 4; ++j) {
      out[j] = f2bf(r0[j]);
      out[j + 4] = f2bf(r0[16 + j]);
    }
  } else {
    int fbase = ft * 128 + k * 32 + lg * 4;
#pragma unroll
    for (int j = 0; j < 4; ++j) {
      out[j] = f2bf(src[(size_t)(fbase + j) * 128 + row]);
      out[j + 4] = f2bf(src[(size_t)(fbase + 16 + j) * 128 + row]);
    }
  }
  short4 a = make_short4(out[0], out[1], out[2], out[3]);
  short4 b = make_short4(out[4], out[5], out[6], out[7]);
  *(short4*)&dst[(size_t)s * 8] = a;
  *(short4*)&dst[(size_t)s * 8 + 4] = b;
}

// ---------------------------------------------------------------------------
// Kernel 1c: W2cat bf16 [336][512], fragment-packed per 32-group, + bias sum.
// ---------------------------------------------------------------------------
__global__ void w2cvt_kernel(const float* __restrict__ Ws2,
                             const float* __restrict__ Wt2,
                             const float* __restrict__ bs2,
                             const float* __restrict__ bt2,
                             short* __restrict__ W2b, float* __restrict__ b2) {
  int i = blockIdx.x * 256 + threadIdx.x;
  if (i < PP) b2[i] = bs2[i] + bt2[i];
  if (i >= PP * 512) return;
  int p = i >> 9, k = i & 511;
  float v = (k < 256) ? Ws2[p * 256 + k] : Wt2[p * 256 + (k - 256)];
  W2b[p * 512 + (k >> 5) * 32 + packpos(k & 31)] = f2bf(v);
}

// ---------------------------------------------------------------------------
// Kernel 2 (v8): MFMA dual-branch GEMM1 + sigmoid, MLP-oriented.
//   Block = 32 n x 128 h x 2 branches; 256 thr / 4 waves; BK=32, 23 steps;
//   grid 1284 (~5 blocks/CU, 4 resident at 36 KB LDS).
//   Wave w: branch (w>>1), h-half (w&1)*64; 8 MFMA + 6 ds_read per step.
//   W: gload_lds from pre-swizzled wimg (4 chunks/wave/step).
//   x: 4 wave-coalesced dword loads/thread + 1 8B ds_write (XOR-slotted).
// ---------------------------------------------------------------------------
__global__ __launch_bounds__(256, 4) void gemm1_mfma(
    const float* __restrict__ x, const short* __restrict__ wimg,
    const float* __restrict__ bs1, const float* __restrict__ bt1,
    short* __restrict__ r2s, short* __restrict__ r2t) {
  __shared__ __align__(16) short wbuf[2][8192];  // 2 x 16 KB
  __shared__ __align__(16) short xbuf[2][1024];  // 2 x 2 KB
  int tid = threadIdx.x;
  int w = tid >> 6, l = tid & 63, lr = l & 15, lg = l >> 4;
  int br = w >> 1, hb = (w & 1) * 64;
  int nb = blockIdx.x * 32;  // 41088 = 1284*32 exact

  // x gather mapping: thread = (krow 0..7, xcol 0..31)
  int xcol = tid & 31, krow = tid >> 5;
  int xn = nb + xcol;
  int xb_ = xn / CC, xc_ = xn - xb_ * CC;
  const float* xptr = x + (size_t)xb_ * (LL * CC) + xc_;
  int xrow = xcol >> 1;
  int xslot = ((xcol & 1) * 4 + (krow & 3)) ^ (xrow & 7);
  int xdst = xrow * 64 + xslot * 8 + (krow >> 2) * 4;

  // W staging: wave w stages 4 KB region [w*2048 .. +2048) shorts
  const short* wsrc = wimg + (size_t)w * 2048 + l * 8;

  f32x4 acc[4][2];  // [ht][n-grp]
#pragma unroll
  for (int i = 0; i < 4; ++i)
#pragma unroll
    for (int g = 0; g < 2; ++g) acc[i][g] = (f32x4){0.f, 0.f, 0.f, 0.f};

  // ---- prologue: stage step 0 ----
  {
#pragma unroll
    for (int i = 0; i < 4; ++i)
      gload_lds16(wsrc + i * 512, &wbuf[0][w * 2048 + i * 512]);
    float xf[4];
#pragma unroll
    for (int j = 0; j < 4; ++j) xf[j] = xptr[(size_t)(krow * 4 + j) * CC];
    short4 v = make_short4(f2bf(xf[0]), f2bf(xf[1]), f2bf(xf[2]), f2bf(xf[3]));
    *(short4*)&xbuf[0][xdst] = v;
  }
  __syncthreads();

  int cur = 0;
  for (int s = 0; s < NSTEP; ++s) {
    // prefetch next step (issue loads first: T14 order)
    float xf[4];
    if (s < NSTEP - 1) {
      int kbase = (s + 1) * 32 + krow * 4;
#pragma unroll
      for (int j = 0; j < 4; ++j) {
        int k = kbase + j;
        xf[j] = (k < LL) ? xptr[(size_t)k * CC] : 0.f;
      }
      const short* ws = wsrc + (size_t)(s + 1) * 8192;
#pragma unroll
      for (int i = 0; i < 4; ++i)
        gload_lds16(ws + i * 512, &wbuf[cur ^ 1][w * 2048 + i * 512]);
    }

    // compute current step
    const short* tw = &wbuf[cur][0];
    const short* tx = &xbuf[cur][0];
    bf16x8 bx[2];
#pragma unroll
    for (int g = 0; g < 2; ++g) {
      int cc = g * 16 + lr;
      int row = cc >> 1;
      int slot = ((cc & 1) * 4 + lg) ^ (row & 7);
      bx[g] = *(const bf16x8*)&tx[row * 64 + slot * 8];
    }
#pragma unroll
    for (int ht = 0; ht < 4; ++ht) {
      int h = hb + ht * 16 + lr;
      int slot = (br * 4 + lg) ^ (h & 7);
      bf16x8 a = *(const bf16x8*)&tw[h * 64 + slot * 8];
      acc[ht][0] =
          __builtin_amdgcn_mfma_f32_16x16x32_bf16(a, bx[0], acc[ht][0], 0, 0, 0);
      acc[ht][1] =
          __builtin_amdgcn_mfma_f32_16x16x32_bf16(a, bx[1], acc[ht][1], 0, 0, 0);
    }

    // write next x tile (late: waits only on its own loads)
    if (s < NSTEP - 1) {
      short4 v = make_short4(f2bf(xf[0]), f2bf(xf[1]), f2bf(xf[2]), f2bf(xf[3]));
      *(short4*)&xbuf[cur ^ 1][xdst] = v;
    }
    __syncthreads();
    cur ^= 1;
  }

  // epilogue: sigmoid -> PACKED bf16 R at shorts [128..255] of each r2 row
  const float* bias = br ? bt1 : bs1;
  short* r2 = br ? r2t : r2s;
#pragma unroll
  for (int ht = 0; ht < 4; ++ht) {
    int h0 = hb + ht * 16 + lg * 4;
    int dst = (h0 >> 5) * 32 + lg * 8 + ((h0 >> 4) & 1) * 4;
    float4 bi = *(const float4*)&bias[h0];
    const float* pb = &bi.x;
#pragma unroll
    for (int g = 0; g < 2; ++g) {
      int n = nb + g * 16 + lr;
      short4 v;
      short* pv = &v.x;
#pragma unroll
      for (int j = 0; j < 4; ++j)
        pv[j] = f2bf(1.f / (1.f + __expf(-(acc[ht][g][j] + pb[j]))));
      *(short4*)&r2[(size_t)n * 256 + 128 + dst] = v;
    }
  }
}

// ---------------------------------------------------------------------------
// Kernel 3: pipelined MFMA memory-enhance (unchanged).
// ---------------------------------------------------------------------------
__global__ __launch_bounds__(256) void memenh_mfma(
    const short* __restrict__ stgS, const short* __restrict__ stgT,
    short* __restrict__ r2s, short* __restrict__ r2t) {
  int br = blockIdx.y;
  const short* stg = br ? stgT : stgS;
  short* r2 = br ? r2t : r2s;

  __shared__ __align__(16) short buf[2][16384];  // 64 KB
  int tid = threadIdx.x;
  int l = tid & 63, lr = l & 15, lg = l >> 4;
  int wbase = tid & 192;
  int n = blockIdx.x * 64 + (tid >> 6) * 16 + lr;

  bf16x8 brag[4];
  {
    const short* rb = r2 + (size_t)n * 256 + 128;
#pragma unroll
    for (int k = 0; k < 4; ++k)
      brag[k] = *(const bf16x8*)&rb[k * 32 + lg * 8];
  }

#define STAGE(t, bsel)                                                        \
  {                                                                           \
    const short* g = stg + (size_t)(t)*16384;                                 \
    _Pragma("unroll") for (int i = 0; i < 8; ++i) {                           \
      gload_lds16(g + (size_t)(i * 256 + tid) * 8,                            \
                  &buf[bsel][(i * 256 + wbase) * 8]);                         \
    }                                                                         \
  }

  STAGE(0, 0);
  __syncthreads();

  f32x4 accO[8];
#pragma unroll
  for (int i = 0; i < 8; ++i) accO[i] = (f32x4){0.f, 0.f, 0.f, 0.f};
  bf16x8 pb[4];
  float ssum = 0.f;
  int cur = 0;

#pragma unroll
  for (int t = 0; t < 8; ++t) {
    if (t < 7) STAGE(t + 1, cur ^ 1);
    const short* tb = &buf[cur][0];
    if ((t & 1) == 0) {
      f32x4 sc[8];
#pragma unroll
      for (int ft16 = 0; ft16 < 8; ++ft16) {
        f32x4 a = {0.f, 0.f, 0.f, 0.f};
#pragma unroll
        for (int k = 0; k < 4; ++k) {
          int row = ft16 * 16 + lr;
          int slot = (4 * k + lg) ^ (row & 7);
          bf16x8 af = *(const bf16x8*)&tb[row * 128 + slot * 8];
          a = __builtin_amdgcn_mfma_f32_16x16x32_bf16(af, brag[k], a, 0, 0, 0);
        }
        sc[ft16] = a;
      }
#pragma unroll
      for (int i = 0; i < 8; ++i) {
        f32x4 v = sc[i];
#pragma unroll
        for (int j = 0; j < 4; ++j) {
          float e = __expf(v[j]);
          v[j] = e;
          ssum += e;
        }
        sc[i] = v;
      }
#pragma unroll
      for (int t4 = 0; t4 < 4; ++t4) {
        f32x4 e0 = sc[2 * t4], e1 = sc[2 * t4 + 1];
        bf16x8 f;
        f[0] = f2bf(e0[0]); f[1] = f2bf(e0[1]);
        f[2] = f2bf(e0[2]); f[3] = f2bf(e0[3]);
        f[4] = f2bf(e1[0]); f[5] = f2bf(e1[1]);
        f[6] = f2bf(e1[2]); f[7] = f2bf(e1[3]);
        pb[t4] = f;
      }
    } else {
#pragma unroll
      for (int dt = 0; dt < 8; ++dt) {
#pragma unroll
        for (int k = 0; k < 4; ++k) {
          int row = dt * 16 + lr;
          int slot = (4 * k + lg) ^ (row & 7);
          bf16x8 af = *(const bf16x8*)&tb[row * 128 + slot * 8];
          accO[dt] =
              __builtin_amdgcn_mfma_f32_16x16x32_bf16(af, pb[k], accO[dt], 0, 0, 0);
        }
      }
    }
    __syncthreads();
    cur ^= 1;
  }
#undef STAGE

  ssum += __shfl_xor(ssum, 16);
  ssum += __shfl_xor(ssum, 32);
  float inv = 1.f / ssum;
  short* rowO = r2 + (size_t)n * 256;
#pragma unroll
  for (int dt = 0; dt < 8; ++dt) {
    short4 o;
    o.x = f2bf(accO[dt][0] * inv);
    o.y = f2bf(accO[dt][1] * inv);
    o.z = f2bf(accO[dt][2] * inv);
    o.w = f2bf(accO[dt][3] * inv);
    *(short4*)&rowO[(dt >> 1) * 32 + lg * 8 + (dt & 1) * 4] = o;
  }
}

// ---------------------------------------------------------------------------
// Kernel 4: MFMA GEMM2 (bf16, K=512 concat, packed operands) + bias +
//   transposed store (unchanged).
// ---------------------------------------------------------------------------
__global__ __launch_bounds__(512) void gemm2_mfma(
    const short* __restrict__ r2s, const short* __restrict__ r2t,
    const short* __restrict__ W2b,  // [336][512] bf16 packed
    const float* __restrict__ b2,   // [336]
    float* __restrict__ out) {
  __shared__ __align__(16) short w2lds[2][112 * 40];  // 17.9 KB
  int tid = threadIdx.x;
  int w = tid >> 6, l = tid & 63, lr = l & 15, lg = l >> 4;
  int p0 = blockIdx.y * 112;
  int n = blockIdx.x * 128 + w * 16 + lr;
  int b = n / CC, c = n - b * CC;
  const short* rs = r2s + (size_t)n * 256;
  const short* rt = r2t + (size_t)n * 256;

  bool dostage = tid < 448;
  int row = tid >> 2, q = tid & 3;
  const short* gW = W2b + (size_t)(p0 + row) * 512 + q * 8;
  int doff = row * 40 + q * 8;

  f32x4 acc[7];
#pragma unroll
  for (int i = 0; i < 7; ++i) acc[i] = (f32x4){0.f, 0.f, 0.f, 0.f};

  if (dostage) *(int4*)&w2lds[0][doff] = *(const int4*)gW;
  __syncthreads();

  int cur = 0;
  for (int step = 0; step < 16; ++step) {
    int k0 = step * 32;
    const short* rrow = ((k0 < 256) ? rs : rt) + (k0 & 255);
    bf16x8 bfr = *(const bf16x8*)&rrow[lg * 8];
    int4 nxt = {0, 0, 0, 0};
    if (step < 15 && dostage) nxt = *(const int4*)(gW + (step + 1) * 32);
    const short* tw = &w2lds[cur][0];
#pragma unroll
    for (int pt = 0; pt < 7; ++pt) {
      bf16x8 a = *(const bf16x8*)&tw[(pt * 16 + lr) * 40 + lg * 8];
      acc[pt] = __builtin_amdgcn_mfma_f32_16x16x32_bf16(a, bfr, acc[pt], 0, 0, 0);
    }
    if (step < 15 && dostage) *(int4*)&w2lds[cur ^ 1][doff] = nxt;
    __syncthreads();
    cur ^= 1;
  }

  size_t obase = (size_t)b * ((size_t)PP * CC) + c;
#pragma unroll
  for (int pt = 0; pt < 7; ++pt) {
    int p = p0 + pt * 16 + lg * 4;
    float4 bias = *(const float4*)&b2[p];
    const float* pb = &bias.x;
#pragma unroll
    for (int j = 0; j < 4; ++j) {
      out[obase + (size_t)(p + j) * CC] = acc[pt][j] + pb[j];
    }
  }
}

// ---------------------------------------------------------------------------
extern "C" void kernel_launch(void* const* d_in, const int* in_sizes, int n_in,
                              void* d_out, int out_size, void* d_ws, size_t ws_size,
                              hipStream_t stream) {
  const float* x    = (const float*)d_in[0];
  const float* Ws1  = (const float*)d_in[1];
  const float* bs1  = (const float*)d_in[2];
  const float* Ws2  = (const float*)d_in[3];
  const float* bs2  = (const float*)d_in[4];
  const float* Wt1  = (const float*)d_in[5];
  const float* bt1  = (const float*)d_in[6];
  const float* Wt2  = (const float*)d_in[7];
  const float* bt2  = (const float*)d_in[8];
  const float* memS = (const float*)d_in[9];
  const float* memT = (const float*)d_in[10];
  float* out = (float*)d_out;

  const size_t N = (size_t)BB * CC;          // 41088
  short* r2s  = (short*)d_ws;                // [N][256] bf16 packed: [O | R]
  short* r2t  = r2s + N * 256;
  short* wimg = r2t + N * 256;               // [23][128][128B] = 368 KB
  short* stgS = wimg + (size_t)NSTEP * 128 * 64;
  short* stgT = stgS + (size_t)16384 * 8;
  short* W2b  = stgT + (size_t)16384 * 8;    // [336][512] bf16 packed
  float* b2   = (float*)(W2b + (size_t)PP * 512);

  // 1. precompute weights / staged conversions
  weff_kernel<<<(HH * NSTEP * 32 + 255) / 256, 256, 0, stream>>>(Ws1, Wt1, wimg);
  memstage_kernel<<<128, 256, 0, stream>>>(memS, memT, stgS, stgT);
  w2cvt_kernel<<<(PP * 512) / 256, 256, 0, stream>>>(Ws2, Wt2, bs2, bt2, W2b, b2);

  // 2. MFMA GEMM1 + sigmoid (both branches), BK=32, grid 1284
  gemm1_mfma<<<1284, 256, 0, stream>>>(x, wimg, bs1, bt1, r2s, r2t);

  // 3. pipelined MFMA memory enhance, both branches in one dispatch
  dim3 g3(642, 2);
  memenh_mfma<<<g3, 256, 0, stream>>>(stgS, stgT, r2s, r2t);

  // 4. MFMA GEMM2 + bias + transposed store
  dim3 g2(321, 3);
  gemm2_mfma<<<g2, 512, 0, stream>>>(r2s, r2t, W2b, b2, out);
}